// Round 1
// baseline (302.061 us; speedup 1.0000x reference)
//
#include <hip/hip_runtime.h>
#include <math.h>

// Problem constants (match reference):
//   D_M = 1024, VOCAB = 50257, BASE = 10000.0, B = 8, S = 4096
// out[b,s,d] = emb_table[x[b,s], d] + pe[s,d]
//   pe[s, 2i]   = sin(s * base^(-2i/D))
//   pe[s, 2i+1] = cos(s * base^(-2i/D))

#define D_M 1024
#define SEQ 4096

__global__ __launch_bounds__(256) void SinusoidalEmbedding_83030307766274_kernel(
    const int* __restrict__ x,
    const float* __restrict__ emb_table,
    float* __restrict__ out)
{
    const int t  = blockIdx.x;          // token index in [0, B*S)
    const int d4 = threadIdx.x;         // float4 index within row, [0, 256)
    const int s  = t & (SEQ - 1);       // position within sequence (S = 4096, power of 2)

    const int row = x[t];               // block-uniform -> scalar load
    const float4* __restrict__ src = (const float4*)(emb_table + (size_t)row * D_M);
    float4 v = src[d4];

    // Columns d = 4*d4 .. 4*d4+3 correspond to (sin,cos) pairs i0 = 2*d4 and i0+1.
    // inv_freq(i) = 10000^(-2i/D) = exp2(i * c), c = -2*log2(10000)/D
    const float c = -2.0f * 13.28771237954945f / (float)D_M;
    const float i0 = (float)(2 * d4);
    const float f0 = exp2f(i0 * c);
    const float f1 = exp2f((i0 + 1.0f) * c);
    const float sp = (float)s;

    float s0, c0, s1, c1;
    sincosf(sp * f0, &s0, &c0);
    sincosf(sp * f1, &s1, &c1);

    v.x += s0;  // even col: sin
    v.y += c0;  // odd  col: cos
    v.z += s1;
    v.w += c1;

    ((float4*)out)[(size_t)t * (D_M / 4) + d4] = v;
}

extern "C" void kernel_launch(void* const* d_in, const int* in_sizes, int n_in,
                              void* d_out, int out_size, void* d_ws, size_t ws_size,
                              hipStream_t stream)
{
    const int*   x         = (const int*)d_in[0];     // [B, S] token ids
    const float* emb_table = (const float*)d_in[1];   // [VOCAB, D_M] fp32
    float*       out       = (float*)d_out;           // [B, S, D_M] fp32

    const int n_tokens = in_sizes[0];                 // B * S = 32768
    SinusoidalEmbedding_83030307766274_kernel<<<n_tokens, 256, 0, stream>>>(x, emb_table, out);
}